// Round 8
// baseline (10863.081 us; speedup 1.0000x reference)
//
#include <hip/hip_runtime.h>
#include <math.h>

#define B     512
#define SEQL  128
#define PT    5
#define EH    256
#define ZS    128
#define DH    512
#define NM    20
#define NMAXT 256

__device__ __forceinline__ float sigf(float x) { return 1.0f / (1.0f + expf(-x)); }

// acc[m][0..7] += av * {lo,hi}
#define FMA8(m, av, lo, hi)                                                   \
    acc[m][0]=fmaf(av,lo.x,acc[m][0]); acc[m][1]=fmaf(av,lo.y,acc[m][1]);     \
    acc[m][2]=fmaf(av,lo.z,acc[m][2]); acc[m][3]=fmaf(av,lo.w,acc[m][3]);     \
    acc[m][4]=fmaf(av,hi.x,acc[m][4]); acc[m][5]=fmaf(av,hi.y,acc[m][5]);     \
    acc[m][6]=fmaf(av,hi.z,acc[m][6]); acc[m][7]=fmaf(av,hi.w,acc[m][7]);

#define XSUM(v) v += __shfl_xor(v,1); v += __shfl_xor(v,2); v += __shfl_xor(v,4); \
                v += __shfl_xor(v,8); v += __shfl_xor(v,16); v += __shfl_xor(v,32);

// GMM sampler body: y[128] in LDS, writes out[(step*B + b)*5]
__device__ __forceinline__ void gmm_sample(
    const float* __restrict__ y, const float* __restrict__ geps,
    const float* __restrict__ penu, float* __restrict__ out,
    int step, int b, int lane)
{
    const int m = lane;
    float pv = (m < NM) ? y[6 * m] : -1e30f;
    float mm = pv;
    mm = fmaxf(mm, __shfl_xor(mm, 1));  mm = fmaxf(mm, __shfl_xor(mm, 2));
    mm = fmaxf(mm, __shfl_xor(mm, 4));  mm = fmaxf(mm, __shfl_xor(mm, 8));
    mm = fmaxf(mm, __shfl_xor(mm, 16)); mm = fmaxf(mm, __shfl_xor(mm, 32));
    float pe = 0.f, tx = 0.f, ty = 0.f;
    if (m < NM) {
        pe = expf(pv - mm);
        const float mx = y[6 * m + 1], my = y[6 * m + 2];
        const float sx = expf(y[6 * m + 3]), sy = expf(y[6 * m + 4]);
        const float cor = tanhf(y[6 * m + 5]);
        const float l21 = cor / sx;
        const float l22 = sqrtf(fmaxf(sy * sy - l21 * l21, 1e-6f));
        const float* ep = &geps[(((size_t)step * B) + b) * (NM * 2) + 2 * m];
        const float e1 = ep[0], e2 = ep[1];
        tx = pe * fmaf(sx, e1, mx);
        ty = pe * (my + fmaf(l21, e1, l22 * e2));
    }
    XSUM(pe) XSUM(tx) XSUM(ty)
    if (lane == 0) {
        const float q0 = y[120], q1 = y[121], q2 = y[122];
        const float qm = fmaxf(q0, fmaxf(q1, q2));
        const float e0 = expf(q0 - qm), e1q = expf(q1 - qm), e2q = expf(q2 - qm);
        const float qs = e0 + e1q + e2q;
        const float* u = &penu[(((size_t)step * B) + b) * 3];
        float* o = &out[(((size_t)step * B) + b) * 5];
        o[0] = tx / pe;
        o[1] = ty / pe;
        o[2] = (u[0] < e0  / qs) ? 1.f : 0.f;
        o[3] = (u[1] < e1q / qs) ? 1.f : 0.f;
        o[4] = (u[2] < e2q / qs) ? 1.f : 0.f;
    }
}

// ---------- generic transpose with zero-pad: out[c*rpad + r] (per z-slice) ----------
__global__ void transpose_pad(const float* __restrict__ in, float* __restrict__ out,
                              int rows, int cols, int rpad, long islice, long oslice)
{
    const float* ip = in + (size_t)blockIdx.z * islice;
    float* op = out + (size_t)blockIdx.z * oslice;
    int idx = blockIdx.x * 256 + threadIdx.x;
    if (idx >= cols * rpad) return;
    int c = idx / rpad, r = idx - c * rpad;
    op[idx] = (r < rows) ? ip[(size_t)r * cols + c] : 0.0f;
}

// =======================================================================
// Encoder step (unchanged from R7). grid 512, block 512 = 8 waves.
// =======================================================================
__global__ __launch_bounds__(512, 4) void enc_step5(
    const float* __restrict__ sT,   // [SEQL][PT][B]
    const float* __restrict__ WihF, const float* __restrict__ WhhF, const float* __restrict__ bF,
    const float* __restrict__ WihB, const float* __restrict__ WhhB, const float* __restrict__ bB,
    const float* __restrict__ hfin, float* __restrict__ hfout, float* __restrict__ cf,
    const float* __restrict__ hbin, float* __restrict__ hbout, float* __restrict__ cb,
    int t)
{
    __shared__ float lds[17408];

    const int tid = threadIdx.x;
    const int x   = blockIdx.x;
    const int ng  = x & 31;
    const int bg  = (x >> 5) & 7;
    const int dir = x >> 8;
    const int n0  = ng * 8;
    const int b0  = bg * 64;

    const float* Whh  = dir ? WhhB : WhhF;
    const float* Wih  = dir ? WihB : WihF;
    const float* bias = dir ? bB   : bF;
    const float* hin  = dir ? hbin : hfin;
    float* hout       = dir ? hbout: hfout;
    float* c          = dir ? cb   : cf;
    const int ts = dir ? (SEQL - 1 - t) : t;

    const int pn = tid & 7;
    const int pc = tid >> 3;
    const int pb = b0 + pc;
    const size_t pidx = (size_t)(n0 + pn) * B + pb;
    const float cold = c[pidx];
    const float x0 = sT[((size_t)ts * PT + 0) * B + pb];
    const float x1 = sT[((size_t)ts * PT + 1) * B + pb];
    const float x2 = sT[((size_t)ts * PT + 2) * B + pb];
    const float x3 = sT[((size_t)ts * PT + 3) * B + pb];
    const float x4 = sT[((size_t)ts * PT + 4) * B + pb];

    #pragma unroll
    for (int i = 0; i < 4; ++i) {
        const int fidx = i * 512 + tid;
        const int w   = fidx >> 9;
        const int rem = fidx & 511;
        const int r   = rem >> 4, s5 = rem & 15;
        const int g   = r >> 3, nn = r & 7;
        const float4 wv4 = *(const float4*)&Whh[(size_t)(g * EH + n0 + nn) * EH + w * 64 + s5 * 4];
        *(float4*)&lds[((w * 32 + r) * 16 + (s5 ^ ((r >> 2) & 7))) * 4] = wv4;
    }
    __syncthreads();

    const int lane = tid & 63;
    const int wv   = tid >> 6;
    const int ri   = lane & 7;
    const int bi   = lane >> 3;
    const int wq   = wv >> 1;
    const int sb   = (wv & 1) * 8;
    const float* hcol = hin + b0 + bi * 8;

    float acc[4][8];
    #pragma unroll
    for (int m = 0; m < 4; ++m)
        #pragma unroll
        for (int j = 0; j < 8; ++j) acc[m][j] = 0.0f;

    #pragma unroll 2
    for (int j4 = 0; j4 < 8; ++j4) {
        float4 a[4];
        #pragma unroll
        for (int m = 0; m < 4; ++m)
            a[m] = *(const float4*)&lds[((wq * 32 + ri * 4 + m) * 16 + (sb | (j4 ^ ri))) * 4];
        const int kb = wv * 32 + j4 * 4;
        #pragma unroll
        for (int jj = 0; jj < 4; ++jj) {
            const float* hp = hcol + (size_t)(kb + jj) * B;
            const float4 blo = *(const float4*)hp;
            const float4 bhi = *(const float4*)(hp + 4);
            #pragma unroll
            for (int m = 0; m < 4; ++m) {
                const float av = (jj == 0) ? a[m].x : (jj == 1) ? a[m].y : (jj == 2) ? a[m].z : a[m].w;
                FMA8(m, av, blo, bhi)
            }
        }
    }
    __syncthreads();

    #pragma unroll
    for (int m = 0; m < 4; ++m) {
        float* pr = &lds[(wv * 32 + ri * 4 + m) * 68 + bi * 8];
        *(float4*)pr       = make_float4(acc[m][0], acc[m][1], acc[m][2], acc[m][3]);
        *(float4*)(pr + 4) = make_float4(acc[m][4], acc[m][5], acc[m][6], acc[m][7]);
    }
    __syncthreads();

    float ps[4];
    #pragma unroll
    for (int g = 0; g < 4; ++g) {
        const int r = g * 8 + pn;
        float v = 0.0f;
        #pragma unroll
        for (int w8 = 0; w8 < 8; ++w8) v += lds[(w8 * 32 + r) * 68 + pc];
        ps[g] = v;
    }

    float gv[4];
    #pragma unroll
    for (int g = 0; g < 4; ++g) {
        const int grow = g * EH + n0 + pn;
        const float* wr = Wih + (size_t)grow * PT;
        float v = ps[g] + bias[grow];
        v = fmaf(x0, wr[0], v); v = fmaf(x1, wr[1], v); v = fmaf(x2, wr[2], v);
        v = fmaf(x3, wr[3], v); v = fmaf(x4, wr[4], v);
        gv[g] = v;
    }
    const float cv = sigf(gv[1]) * cold + sigf(gv[0]) * tanhf(gv[2]);
    c[pidx] = cv;
    hout[pidx] = sigf(gv[3]) * tanhf(cv);
}

// =======================================================================
// Fused decoder step + previous-step sampler.
// grid 512 (= 2 blocks/CU exactly, all co-resident): ng = x&63, bg = x>>6.
// Phase 1 (t>0, ng<16): ysamp(t-1) for 4 batches -> out[t-1], release flag.
// Phase 2 (all): G GEMM; epilogue acquires flag, reads out[t-1].
// =======================================================================
__global__ __launch_bounds__(512, 4) void dec_fused(
    const float* __restrict__ hin, float* __restrict__ hout, float* __restrict__ cT,
    const float* __restrict__ CzT, const float* __restrict__ Whh,
    const float* __restrict__ Wih, const float* __restrict__ WdecT,
    const float* __restrict__ bdec,
    const float* __restrict__ geps, const float* __restrict__ penu,
    float* __restrict__ out, int* __restrict__ flags, int t)
{
    __shared__ float lds[17408];

    const int tid = threadIdx.x;
    const int x   = blockIdx.x;
    const int ng  = x & 63;
    const int bg  = x >> 6;
    const int n0  = ng * 8;
    const int b0  = bg * 64;

    // ---------- phase 1: sampler for step t-1 (128 producer blocks) ----------
    if (t > 0 && ng < 16) {
        const int tprev = t - 1;
        const int yb0 = b0 + ng * 4;
        float* h_s  = lds;          // [512][4]
        float* part = lds + 2048;   // [512][4] by (ks*128+col)
        float* Y    = lds + 4096;   // [4][128]

        *(float4*)&h_s[tid * 4] = *(const float4*)&hin[(size_t)tid * B + yb0];
        __syncthreads();

        const int col = tid & 127;
        const int ks  = tid >> 7;
        float a0 = 0.f, a1 = 0.f, a2 = 0.f, a3 = 0.f;
        const float* wp = WdecT + (size_t)ks * 128 * 128 + col;
        #pragma unroll 8
        for (int k = 0; k < 128; ++k) {
            const float w = wp[(size_t)k * 128];
            const float4 hq = *(const float4*)&h_s[(ks * 128 + k) * 4];
            a0 = fmaf(w, hq.x, a0); a1 = fmaf(w, hq.y, a1);
            a2 = fmaf(w, hq.z, a2); a3 = fmaf(w, hq.w, a3);
        }
        float* pc4 = &part[(ks * 128 + col) * 4];
        pc4[0] = a0; pc4[1] = a1; pc4[2] = a2; pc4[3] = a3;
        __syncthreads();
        if (ks == 0) {
            const float bd = (col < 123) ? bdec[col] : 0.0f;
            #pragma unroll
            for (int j = 0; j < 4; ++j)
                Y[j * 128 + col] = part[(0 * 128 + col) * 4 + j] + part[(128 + col) * 4 + j]
                                 + part[(256 + col) * 4 + j] + part[(384 + col) * 4 + j] + bd;
        }
        __syncthreads();
        if (tid < 256)
            gmm_sample(&Y[(tid >> 6) * 128], geps, penu, out, tprev, yb0 + (tid >> 6), tid & 63);
        __syncthreads();
        if (tid == 0) {
            __threadfence();
            __hip_atomic_fetch_add(&flags[tprev * 8 + bg], 1, __ATOMIC_RELEASE, __HIP_MEMORY_SCOPE_AGENT);
        }
        // no barrier needed: lds reads all completed before previous barrier
    }

    // ---------- phase 2: gate GEMM ----------
    const int pn = tid & 7;
    const int pc = tid >> 3;
    const int pb = b0 + pc;
    const size_t pidx = (size_t)(n0 + pn) * B + pb;
    const float cold = cT[pidx];
    float cz[4];
    #pragma unroll
    for (int g = 0; g < 4; ++g)
        cz[g] = CzT[(size_t)(g * DH + n0 + pn) * B + pb];

    __syncthreads();   // phase-1 lds safety before W staging
    #pragma unroll
    for (int i = 0; i < 8; ++i) {
        const int fidx = i * 512 + tid;
        const int w   = fidx >> 10;
        const int rem = fidx & 1023;
        const int r   = rem >> 5, s5 = rem & 31;
        const int g   = r >> 3, nn = r & 7;
        const int sl  = (s5 & 16) | ((s5 & 15) ^ ((r >> 2) & 7));
        const float4 wv4 = *(const float4*)&Whh[(size_t)(g * DH + n0 + nn) * DH + w * 128 + s5 * 4];
        *(float4*)&lds[((w * 32 + r) * 32 + sl) * 4] = wv4;
    }
    __syncthreads();

    const int lane = tid & 63;
    const int wv   = tid >> 6;
    const int ri   = lane & 7;
    const int bi   = lane >> 3;
    const int wq   = wv >> 1;
    const int sb   = (wv & 1) * 16;
    const float* hcol = hin + b0 + bi * 8;

    float acc[4][8];
    #pragma unroll
    for (int m = 0; m < 4; ++m)
        #pragma unroll
        for (int j = 0; j < 8; ++j) acc[m][j] = 0.0f;

    #pragma unroll 2
    for (int j4 = 0; j4 < 16; ++j4) {
        float4 a[4];
        #pragma unroll
        for (int m = 0; m < 4; ++m)
            a[m] = *(const float4*)&lds[((wq * 32 + ri * 4 + m) * 32 + (sb | (j4 ^ ri))) * 4];
        const int kb = wv * 64 + j4 * 4;
        #pragma unroll
        for (int jj = 0; jj < 4; ++jj) {
            const float* hp = hcol + (size_t)(kb + jj) * B;
            const float4 blo = *(const float4*)hp;
            const float4 bhi = *(const float4*)(hp + 4);
            #pragma unroll
            for (int m = 0; m < 4; ++m) {
                const float av = (jj == 0) ? a[m].x : (jj == 1) ? a[m].y : (jj == 2) ? a[m].z : a[m].w;
                FMA8(m, av, blo, bhi)
            }
        }
    }
    __syncthreads();

    #pragma unroll
    for (int m = 0; m < 4; ++m) {
        float* pr = &lds[(wv * 32 + ri * 4 + m) * 68 + bi * 8];
        *(float4*)pr       = make_float4(acc[m][0], acc[m][1], acc[m][2], acc[m][3]);
        *(float4*)(pr + 4) = make_float4(acc[m][4], acc[m][5], acc[m][6], acc[m][7]);
    }
    __syncthreads();

    float ps[4];
    #pragma unroll
    for (int g = 0; g < 4; ++g) {
        const int r = g * 8 + pn;
        float v = 0.0f;
        #pragma unroll
        for (int w8 = 0; w8 < 8; ++w8) v += lds[(w8 * 32 + r) * 68 + pc];
        ps[g] = v;
    }

    // ---------- acquire out[t-1], then pointwise ----------
    float p0, p1, p2, p3, p4;
    if (t == 0) { p0 = 0.f; p1 = 0.f; p2 = 1.f; p3 = 0.f; p4 = 0.f; }
    else {
        if (tid == 0) {
            while (__hip_atomic_load(&flags[(t - 1) * 8 + bg], __ATOMIC_ACQUIRE, __HIP_MEMORY_SCOPE_AGENT) < 16)
                __builtin_amdgcn_s_sleep(1);
        }
        __syncthreads();
        const float* pp = &out[((size_t)(t - 1) * B + pb) * 5];
        p0 = pp[0]; p1 = pp[1]; p2 = pp[2]; p3 = pp[3]; p4 = pp[4];
    }

    float gv[4];
    #pragma unroll
    for (int g = 0; g < 4; ++g) {
        const int grow = g * DH + n0 + pn;
        const float* wr = Wih + (size_t)grow * 133;
        float v = ps[g] + cz[g];
        v = fmaf(p0, wr[0], v); v = fmaf(p1, wr[1], v); v = fmaf(p2, wr[2], v);
        v = fmaf(p3, wr[3], v); v = fmaf(p4, wr[4], v);
        gv[g] = v;
    }
    const float cv = sigf(gv[1]) * cold + sigf(gv[0]) * tanhf(gv[2]);
    cT[pidx] = cv;
    hout[pidx] = sigf(gv[3]) * tanhf(cv);
}

// =======================================================================
// Standalone sampler for the final step. grid 128 x 512 thr, 4 batches/block.
// =======================================================================
__global__ __launch_bounds__(512) void ysamp6(
    const float* __restrict__ hT, const float* __restrict__ WdecT,
    const float* __restrict__ bdec,
    const float* __restrict__ geps, const float* __restrict__ penu,
    float* __restrict__ out, int t)
{
    __shared__ float h_s[512][4];
    __shared__ float part[4][128][4];
    __shared__ float Y[4][128];

    const int tid = threadIdx.x;
    const int col = tid & 127;
    const int ks  = tid >> 7;
    const int b0  = blockIdx.x * 4;

    *(float4*)&h_s[tid][0] = *(const float4*)&hT[(size_t)tid * B + b0];
    __syncthreads();

    float a0 = 0.f, a1 = 0.f, a2 = 0.f, a3 = 0.f;
    const float* wp = WdecT + (size_t)ks * 128 * 128 + col;
    #pragma unroll 8
    for (int k = 0; k < 128; ++k) {
        const float w = wp[(size_t)k * 128];
        const float4 hq = *(const float4*)&h_s[ks * 128 + k][0];
        a0 = fmaf(w, hq.x, a0); a1 = fmaf(w, hq.y, a1);
        a2 = fmaf(w, hq.z, a2); a3 = fmaf(w, hq.w, a3);
    }
    part[ks][col][0] = a0; part[ks][col][1] = a1;
    part[ks][col][2] = a2; part[ks][col][3] = a3;
    __syncthreads();
    if (ks == 0) {
        const float bd = (col < 123) ? bdec[col] : 0.0f;
        #pragma unroll
        for (int j = 0; j < 4; ++j)
            Y[j][col] = part[0][col][j] + part[1][col][j] + part[2][col][j]
                      + part[3][col][j] + bd;
    }
    __syncthreads();

    if (tid < 256)
        gmm_sample(Y[tid >> 6], geps, penu, out, t, b0 + (tid >> 6), tid & 63);
}

// ---------------- latent chain ----------------
__global__ __launch_bounds__(256) void latent2(
    const float* __restrict__ hfT, const float* __restrict__ hbT,
    const float* __restrict__ Wmu, const float* __restrict__ bmu,
    const float* __restrict__ Wsig, const float* __restrict__ bsig,
    const float* __restrict__ zepsT, float* __restrict__ zT)
{
    const int lane = threadIdx.x & 63;
    const int wv   = __builtin_amdgcn_readfirstlane(threadIdx.x >> 6);
    const int b    = blockIdx.x * 64 + lane;
    const int n0   = blockIdx.y * 8 + wv * 2;

    float am[2] = {}, as2[2] = {};
    #pragma unroll 4
    for (int k0 = 0; k0 < 2 * EH; k0 += 4) {
        const float* hsrc = (k0 < EH) ? hfT : hbT;
        const int kk = k0 & (EH - 1);
        const float a0 = hsrc[(size_t)(kk + 0) * B + b];
        const float a1 = hsrc[(size_t)(kk + 1) * B + b];
        const float a2 = hsrc[(size_t)(kk + 2) * B + b];
        const float a3 = hsrc[(size_t)(kk + 3) * B + b];
        #pragma unroll
        for (int j = 0; j < 2; ++j) {
            const float4 wm = *(const float4*)&Wmu[((size_t)(n0 + j)) * (2 * EH) + k0];
            const float4 ws = *(const float4*)&Wsig[((size_t)(n0 + j)) * (2 * EH) + k0];
            float u = am[j], v = as2[j];
            u = fmaf(a0, wm.x, u); u = fmaf(a1, wm.y, u); u = fmaf(a2, wm.z, u); u = fmaf(a3, wm.w, u);
            v = fmaf(a0, ws.x, v); v = fmaf(a1, ws.y, v); v = fmaf(a2, ws.z, v); v = fmaf(a3, ws.w, v);
            am[j] = u; as2[j] = v;
        }
    }
    #pragma unroll
    for (int j = 0; j < 2; ++j) {
        const int n = n0 + j;
        const float mu = am[j] + bmu[n];
        const float sg = expf(0.5f * (as2[j] + bsig[n]));
        zT[(size_t)n * B + b] = fmaf(sg, zepsT[(size_t)n * B + b], mu);
    }
}

__global__ __launch_bounds__(256) void h02(
    const float* __restrict__ zT, const float* __restrict__ Wh0,
    const float* __restrict__ bh0, float* __restrict__ hT)
{
    const int lane = threadIdx.x & 63;
    const int wv   = __builtin_amdgcn_readfirstlane(threadIdx.x >> 6);
    const int b    = blockIdx.x * 64 + lane;
    const int n0   = blockIdx.y * 32 + wv * 8;

    float acc[8] = {};
    #pragma unroll 2
    for (int k0 = 0; k0 < ZS; k0 += 4) {
        const float a0 = zT[(size_t)(k0 + 0) * B + b];
        const float a1 = zT[(size_t)(k0 + 1) * B + b];
        const float a2 = zT[(size_t)(k0 + 2) * B + b];
        const float a3 = zT[(size_t)(k0 + 3) * B + b];
        #pragma unroll
        for (int r = 0; r < 8; ++r) {
            const float4 w = *(const float4*)&Wh0[((size_t)(n0 + r)) * ZS + k0];
            float v = acc[r];
            v = fmaf(a0, w.x, v); v = fmaf(a1, w.y, v);
            v = fmaf(a2, w.z, v); v = fmaf(a3, w.w, v);
            acc[r] = v;
        }
    }
    #pragma unroll
    for (int r = 0; r < 8; ++r)
        hT[(size_t)(n0 + r) * B + b] = tanhf(acc[r] + bh0[n0 + r]);
}

__global__ __launch_bounds__(256) void cz2(
    const float* __restrict__ zT, const float* __restrict__ Wih,
    const float* __restrict__ bias, float* __restrict__ CzT)
{
    const int lane = threadIdx.x & 63;
    const int wv   = __builtin_amdgcn_readfirstlane(threadIdx.x >> 6);
    const int b    = blockIdx.x * 64 + lane;
    const int r0   = blockIdx.y * 32 + wv * 8;

    float acc[8] = {};
    #pragma unroll 4
    for (int k = 0; k < ZS; ++k) {
        const float a = zT[(size_t)k * B + b];
        #pragma unroll
        for (int r = 0; r < 8; ++r)
            acc[r] = fmaf(a, Wih[(size_t)(r0 + r) * 133 + 5 + k], acc[r]);
    }
    #pragma unroll
    for (int r = 0; r < 8; ++r)
        CzT[(size_t)(r0 + r) * B + b] = acc[r] + bias[r0 + r];
}

extern "C" void kernel_launch(void* const* d_in, const int* in_sizes, int n_in,
                              void* d_out, int out_size, void* d_ws, size_t ws_size,
                              hipStream_t stream)
{
    (void)in_sizes; (void)n_in; (void)out_size; (void)ws_size;

    const float* s      = (const float*)d_in[0];
    const float* WihF   = (const float*)d_in[1];
    const float* WhhF   = (const float*)d_in[2];
    const float* bF     = (const float*)d_in[3];
    const float* WihB   = (const float*)d_in[4];
    const float* WhhB   = (const float*)d_in[5];
    const float* bB     = (const float*)d_in[6];
    const float* Wmu    = (const float*)d_in[7];
    const float* bmu    = (const float*)d_in[8];
    const float* Wsig   = (const float*)d_in[9];
    const float* bsig   = (const float*)d_in[10];
    const float* Wh0    = (const float*)d_in[11];
    const float* bh0    = (const float*)d_in[12];
    const float* decWih = (const float*)d_in[13];
    const float* decWhh = (const float*)d_in[14];
    const float* decB   = (const float*)d_in[15];
    const float* Wdec   = (const float*)d_in[16];
    const float* bdec   = (const float*)d_in[17];
    const float* zeps   = (const float*)d_in[18];
    const float* geps   = (const float*)d_in[19];
    const float* penu   = (const float*)d_in[20];

    float* out = (float*)d_out;
    float* p   = (float*)d_ws;

    float* hf0  = p; p += 131072;   // zeroed...
    float* hb0  = p; p += 131072;
    float* cf   = p; p += 131072;
    float* cb   = p; p += 131072;
    float* cdT  = p; p += 262144;
    int*  flags = (int*)p; p += 2048;  // [256][8], zeroed每 launch
    float* hf1  = p; p += 131072;
    float* hb1  = p; p += 131072;
    float* hA   = p; p += 262144;
    float* hB   = p; p += 262144;
    float* zT   = p; p += 65536;
    float* CzT  = p; p += 1048576;
    float* zepsT= p; p += 65536;
    float* WdecT= p; p += 65536;
    float* sT   = p; p += 327680;   // [128][5][512]

    // zero hf0..cdT + flags (contiguous)
    hipMemsetAsync((void*)hf0, 0, (size_t)(4 * 131072 + 262144 + 2048) * sizeof(float), stream);

    transpose_pad<<<dim3(256, 1, 1), 256, 0, stream>>>(zeps, zepsT, B, ZS, B, 0, 0);
    transpose_pad<<<dim3(256, 1, 1), 256, 0, stream>>>(Wdec, WdecT, 123, DH, 128, 0, 0);
    transpose_pad<<<dim3(10, 1, SEQL), 256, 0, stream>>>(s, sT, B, PT, B, (long)B * PT, (long)B * PT);

    for (int t = 0; t < SEQL; ++t) {
        const float* hfin = (t & 1) ? hf1 : hf0;  float* hfout = (t & 1) ? hf0 : hf1;
        const float* hbin = (t & 1) ? hb1 : hb0;  float* hbout = (t & 1) ? hb0 : hb1;
        enc_step5<<<dim3(512), 512, 0, stream>>>(
            sT, WihF, WhhF, bF, WihB, WhhB, bB,
            hfin, hfout, cf, hbin, hbout, cb, t);
    }
    // t=127 (odd) wrote hf0/hb0
    latent2<<<dim3(8, 16), 256, 0, stream>>>(hf0, hb0, Wmu, bmu, Wsig, bsig, zepsT, zT);
    h02<<<dim3(8, 16), 256, 0, stream>>>(zT, Wh0, bh0, hA);
    cz2<<<dim3(8, 64), 256, 0, stream>>>(zT, decWih, decB, CzT);

    for (int t = 0; t < NMAXT; ++t) {
        const float* hin = (t & 1) ? hB : hA;
        float* hout      = (t & 1) ? hA : hB;
        dec_fused<<<dim3(512), 512, 0, stream>>>(
            hin, hout, cdT, CzT, decWhh, decWih, WdecT, bdec,
            geps, penu, out, flags, t);
    }
    // final sampler: h[255] = hout of t=255 (odd) = hA
    ysamp6<<<dim3(128), 512, 0, stream>>>(hA, WdecT, bdec, geps, penu, out, NMAXT - 1);
}

// Round 9
// 10025.732 us; speedup vs baseline: 1.0835x; 1.0835x over previous
//
#include <hip/hip_runtime.h>
#include <math.h>

#define B     512
#define SEQL  128
#define PT    5
#define EH    256
#define ZS    128
#define DH    512
#define NM    20
#define NMAXT 256

typedef float f2 __attribute__((ext_vector_type(2)));

__device__ __forceinline__ float sigf(float x) { return 1.0f / (1.0f + expf(-x)); }

// packed: acc[m][0..3] (f2 pairs over 8 batches) += ww * {p0..p3}
#define PK4(m, ww, p0, p1, p2, p3)                                \
    acc[m][0] = ww * p0 + acc[m][0]; acc[m][1] = ww * p1 + acc[m][1]; \
    acc[m][2] = ww * p2 + acc[m][2]; acc[m][3] = ww * p3 + acc[m][3];

#define XSUM(v) v += __shfl_xor(v,1); v += __shfl_xor(v,2); v += __shfl_xor(v,4); \
                v += __shfl_xor(v,8); v += __shfl_xor(v,16); v += __shfl_xor(v,32);

// GMM sampler body: y[128] in LDS, writes out[(step*B + b)*5]
__device__ __forceinline__ void gmm_sample(
    const float* __restrict__ y, const float* __restrict__ geps,
    const float* __restrict__ penu, float* __restrict__ out,
    int step, int b, int lane)
{
    const int m = lane;
    float pv = (m < NM) ? y[6 * m] : -1e30f;
    float mm = pv;
    mm = fmaxf(mm, __shfl_xor(mm, 1));  mm = fmaxf(mm, __shfl_xor(mm, 2));
    mm = fmaxf(mm, __shfl_xor(mm, 4));  mm = fmaxf(mm, __shfl_xor(mm, 8));
    mm = fmaxf(mm, __shfl_xor(mm, 16)); mm = fmaxf(mm, __shfl_xor(mm, 32));
    float pe = 0.f, tx = 0.f, ty = 0.f;
    if (m < NM) {
        pe = expf(pv - mm);
        const float mx = y[6 * m + 1], my = y[6 * m + 2];
        const float sx = expf(y[6 * m + 3]), sy = expf(y[6 * m + 4]);
        const float cor = tanhf(y[6 * m + 5]);
        const float l21 = cor / sx;
        const float l22 = sqrtf(fmaxf(sy * sy - l21 * l21, 1e-6f));
        const float* ep = &geps[(((size_t)step * B) + b) * (NM * 2) + 2 * m];
        const float e1 = ep[0], e2 = ep[1];
        tx = pe * fmaf(sx, e1, mx);
        ty = pe * (my + fmaf(l21, e1, l22 * e2));
    }
    XSUM(pe) XSUM(tx) XSUM(ty)
    if (lane == 0) {
        const float q0 = y[120], q1 = y[121], q2 = y[122];
        const float qm = fmaxf(q0, fmaxf(q1, q2));
        const float e0 = expf(q0 - qm), e1q = expf(q1 - qm), e2q = expf(q2 - qm);
        const float qs = e0 + e1q + e2q;
        const float* u = &penu[(((size_t)step * B) + b) * 3];
        float* o = &out[(((size_t)step * B) + b) * 5];
        o[0] = tx / pe;
        o[1] = ty / pe;
        o[2] = (u[0] < e0  / qs) ? 1.f : 0.f;
        o[3] = (u[1] < e1q / qs) ? 1.f : 0.f;
        o[4] = (u[2] < e2q / qs) ? 1.f : 0.f;
    }
}

// ---------- generic transpose with zero-pad: out[c*rpad + r] (per z-slice) ----------
__global__ void transpose_pad(const float* __restrict__ in, float* __restrict__ out,
                              int rows, int cols, int rpad, long islice, long oslice)
{
    const float* ip = in + (size_t)blockIdx.z * islice;
    float* op = out + (size_t)blockIdx.z * oslice;
    int idx = blockIdx.x * 256 + threadIdx.x;
    if (idx >= cols * rpad) return;
    int c = idx / rpad, r = idx - c * rpad;
    op[idx] = (r < rows) ? ip[(size_t)r * cols + c] : 0.0f;
}

// =======================================================================
// Encoder step. grid 512: x = dir*256 + bg*32 + ng. block 512 = 8 waves.
// Tile: 32 gate-rows (4g x 8n) x 64 b. Waves 8-way k-split (32 k each).
// G-phase uses packed f2 math (v_pk_fma_f32).
// =======================================================================
__global__ __launch_bounds__(512, 4) void enc_step6(
    const float* __restrict__ sT,   // [SEQL][PT][B]
    const float* __restrict__ WihF, const float* __restrict__ WhhF, const float* __restrict__ bF,
    const float* __restrict__ WihB, const float* __restrict__ WhhB, const float* __restrict__ bB,
    const float* __restrict__ hfin, float* __restrict__ hfout, float* __restrict__ cf,
    const float* __restrict__ hbin, float* __restrict__ hbout, float* __restrict__ cb,
    int t)
{
    __shared__ float lds[17408];

    const int tid = threadIdx.x;
    const int x   = blockIdx.x;
    const int ng  = x & 31;
    const int bg  = (x >> 5) & 7;
    const int dir = x >> 8;
    const int n0  = ng * 8;
    const int b0  = bg * 64;

    const float* Whh  = dir ? WhhB : WhhF;
    const float* Wih  = dir ? WihB : WihF;
    const float* bias = dir ? bB   : bF;
    const float* hin  = dir ? hbin : hfin;
    float* hout       = dir ? hbout: hfout;
    float* c          = dir ? cb   : cf;
    const int ts = dir ? (SEQL - 1 - t) : t;

    // ---- pointwise-phase prefetch (resolves under G compute) ----
    const int pn = tid & 7;
    const int pc = tid >> 3;
    const int pb = b0 + pc;
    const size_t pidx = (size_t)(n0 + pn) * B + pb;
    const float cold = c[pidx];
    const float x0 = sT[((size_t)ts * PT + 0) * B + pb];
    const float x1 = sT[((size_t)ts * PT + 1) * B + pb];
    const float x2 = sT[((size_t)ts * PT + 2) * B + pb];
    const float x3 = sT[((size_t)ts * PT + 3) * B + pb];
    const float x4 = sT[((size_t)ts * PT + 4) * B + pb];

    // ---- stage W (32 KB): XOR-swizzled ----
    #pragma unroll
    for (int i = 0; i < 4; ++i) {
        const int fidx = i * 512 + tid;
        const int w   = fidx >> 9;
        const int rem = fidx & 511;
        const int r   = rem >> 4, s5 = rem & 15;
        const int g   = r >> 3, nn = r & 7;
        const float4 wv4 = *(const float4*)&Whh[(size_t)(g * EH + n0 + nn) * EH + w * 64 + s5 * 4];
        *(float4*)&lds[((w * 32 + r) * 16 + (s5 ^ ((r >> 2) & 7))) * 4] = wv4;
    }
    __syncthreads();

    const int lane = tid & 63;
    const int wv   = tid >> 6;
    const int ri   = lane & 7;
    const int bi   = lane >> 3;
    const int wq   = wv >> 1;
    const int sb   = (wv & 1) * 8;
    const float* hcol = hin + b0 + bi * 8;

    f2 acc[4][4];
    #pragma unroll
    for (int m = 0; m < 4; ++m)
        #pragma unroll
        for (int j = 0; j < 4; ++j) acc[m][j] = (f2){0.f, 0.f};

    #pragma unroll 2
    for (int j4 = 0; j4 < 8; ++j4) {
        float4 a[4];
        #pragma unroll
        for (int m = 0; m < 4; ++m)
            a[m] = *(const float4*)&lds[((wq * 32 + ri * 4 + m) * 16 + (sb | (j4 ^ ri))) * 4];
        const int kb = wv * 32 + j4 * 4;
        #pragma unroll
        for (int jj = 0; jj < 4; ++jj) {
            const float* hp = hcol + (size_t)(kb + jj) * B;
            const float4 blo = *(const float4*)hp;
            const float4 bhi = *(const float4*)(hp + 4);
            const f2 p0 = {blo.x, blo.y}, p1 = {blo.z, blo.w};
            const f2 p2 = {bhi.x, bhi.y}, p3 = {bhi.z, bhi.w};
            #pragma unroll
            for (int m = 0; m < 4; ++m) {
                const float av = (jj == 0) ? a[m].x : (jj == 1) ? a[m].y : (jj == 2) ? a[m].z : a[m].w;
                const f2 ww = {av, av};
                PK4(m, ww, p0, p1, p2, p3)
            }
        }
    }
    __syncthreads();

    #pragma unroll
    for (int m = 0; m < 4; ++m) {
        float* pr = &lds[(wv * 32 + ri * 4 + m) * 68 + bi * 8];
        *(float4*)pr       = make_float4(acc[m][0].x, acc[m][0].y, acc[m][1].x, acc[m][1].y);
        *(float4*)(pr + 4) = make_float4(acc[m][2].x, acc[m][2].y, acc[m][3].x, acc[m][3].y);
    }
    __syncthreads();

    float ps[4];
    #pragma unroll
    for (int g = 0; g < 4; ++g) {
        const int r = g * 8 + pn;
        float v = 0.0f;
        #pragma unroll
        for (int w8 = 0; w8 < 8; ++w8) v += lds[(w8 * 32 + r) * 68 + pc];
        ps[g] = v;
    }

    float gv[4];
    #pragma unroll
    for (int g = 0; g < 4; ++g) {
        const int grow = g * EH + n0 + pn;
        const float* wr = Wih + (size_t)grow * PT;
        float v = ps[g] + bias[grow];
        v = fmaf(x0, wr[0], v); v = fmaf(x1, wr[1], v); v = fmaf(x2, wr[2], v);
        v = fmaf(x3, wr[3], v); v = fmaf(x4, wr[4], v);
        gv[g] = v;
    }
    const float cv = sigf(gv[1]) * cold + sigf(gv[0]) * tanhf(gv[2]);
    c[pidx] = cv;
    hout[pidx] = sigf(gv[3]) * tanhf(cv);
}

// =======================================================================
// Decoder step. grid 512: ng = x&63, bg = x>>6. block 512 = 8 waves.
// Tile: 32 gate-rows x 64 b. Waves 8-way k-split (64 k each). Packed f2 math.
// =======================================================================
__global__ __launch_bounds__(512, 4) void dec_step6(
    const float* __restrict__ hin, float* __restrict__ hout, float* __restrict__ cT,
    const float* __restrict__ CzT, const float* __restrict__ Whh,
    const float* __restrict__ Wih, const float* __restrict__ prevPt, int t)
{
    __shared__ float lds[17408];

    const int tid = threadIdx.x;
    const int x   = blockIdx.x;
    const int ng  = x & 63;
    const int bg  = x >> 6;
    const int n0  = ng * 8;
    const int b0  = bg * 64;

    // ---- pointwise-phase prefetch ----
    const int pn = tid & 7;
    const int pc = tid >> 3;
    const int pb = b0 + pc;
    const size_t pidx = (size_t)(n0 + pn) * B + pb;
    const float cold = cT[pidx];
    float p0w, p1w, p2w, p3w, p4w;
    if (t == 0) { p0w = 0.f; p1w = 0.f; p2w = 1.f; p3w = 0.f; p4w = 0.f; }
    else {
        const float* pp = &prevPt[(size_t)pb * 5];
        p0w = pp[0]; p1w = pp[1]; p2w = pp[2]; p3w = pp[3]; p4w = pp[4];
    }
    float cz[4];
    #pragma unroll
    for (int g = 0; g < 4; ++g)
        cz[g] = CzT[(size_t)(g * DH + n0 + pn) * B + pb];

    // ---- stage W (64 KB) ----
    #pragma unroll
    for (int i = 0; i < 8; ++i) {
        const int fidx = i * 512 + tid;
        const int w   = fidx >> 10;
        const int rem = fidx & 1023;
        const int r   = rem >> 5, s5 = rem & 31;
        const int g   = r >> 3, nn = r & 7;
        const int sl  = (s5 & 16) | ((s5 & 15) ^ ((r >> 2) & 7));
        const float4 wv4 = *(const float4*)&Whh[(size_t)(g * DH + n0 + nn) * DH + w * 128 + s5 * 4];
        *(float4*)&lds[((w * 32 + r) * 32 + sl) * 4] = wv4;
    }
    __syncthreads();

    const int lane = tid & 63;
    const int wv   = tid >> 6;
    const int ri   = lane & 7;
    const int bi   = lane >> 3;
    const int wq   = wv >> 1;
    const int sb   = (wv & 1) * 16;
    const float* hcol = hin + b0 + bi * 8;

    f2 acc[4][4];
    #pragma unroll
    for (int m = 0; m < 4; ++m)
        #pragma unroll
        for (int j = 0; j < 4; ++j) acc[m][j] = (f2){0.f, 0.f};

    #pragma unroll 2
    for (int j4 = 0; j4 < 16; ++j4) {
        float4 a[4];
        #pragma unroll
        for (int m = 0; m < 4; ++m)
            a[m] = *(const float4*)&lds[((wq * 32 + ri * 4 + m) * 32 + (sb | (j4 ^ ri))) * 4];
        const int kb = wv * 64 + j4 * 4;
        #pragma unroll
        for (int jj = 0; jj < 4; ++jj) {
            const float* hp = hcol + (size_t)(kb + jj) * B;
            const float4 blo = *(const float4*)hp;
            const float4 bhi = *(const float4*)(hp + 4);
            const f2 p0 = {blo.x, blo.y}, p1 = {blo.z, blo.w};
            const f2 p2 = {bhi.x, bhi.y}, p3 = {bhi.z, bhi.w};
            #pragma unroll
            for (int m = 0; m < 4; ++m) {
                const float av = (jj == 0) ? a[m].x : (jj == 1) ? a[m].y : (jj == 2) ? a[m].z : a[m].w;
                const f2 ww = {av, av};
                PK4(m, ww, p0, p1, p2, p3)
            }
        }
    }
    __syncthreads();

    #pragma unroll
    for (int m = 0; m < 4; ++m) {
        float* pr = &lds[(wv * 32 + ri * 4 + m) * 68 + bi * 8];
        *(float4*)pr       = make_float4(acc[m][0].x, acc[m][0].y, acc[m][1].x, acc[m][1].y);
        *(float4*)(pr + 4) = make_float4(acc[m][2].x, acc[m][2].y, acc[m][3].x, acc[m][3].y);
    }
    __syncthreads();

    float ps[4];
    #pragma unroll
    for (int g = 0; g < 4; ++g) {
        const int r = g * 8 + pn;
        float v = 0.0f;
        #pragma unroll
        for (int w8 = 0; w8 < 8; ++w8) v += lds[(w8 * 32 + r) * 68 + pc];
        ps[g] = v;
    }

    float gv[4];
    #pragma unroll
    for (int g = 0; g < 4; ++g) {
        const int grow = g * DH + n0 + pn;
        const float* wr = Wih + (size_t)grow * 133;
        float v = ps[g] + cz[g];
        v = fmaf(p0w, wr[0], v); v = fmaf(p1w, wr[1], v); v = fmaf(p2w, wr[2], v);
        v = fmaf(p3w, wr[3], v); v = fmaf(p4w, wr[4], v);
        gv[g] = v;
    }
    const float cv = sigf(gv[1]) * cold + sigf(gv[0]) * tanhf(gv[2]);
    cT[pidx] = cv;
    hout[pidx] = sigf(gv[3]) * tanhf(cv);
}

// =======================================================================
// Y = h @ Wdec^T + bdec fused with GMM sampler (R7-proven).
// grid 128 blocks x 512 thr; block = 4 batches x 128 cols, 4-way k-split.
// =======================================================================
__global__ __launch_bounds__(512) void ysamp6(
    const float* __restrict__ hT, const float* __restrict__ WdecT,
    const float* __restrict__ bdec,
    const float* __restrict__ geps, const float* __restrict__ penu,
    float* __restrict__ out, int t)
{
    __shared__ float h_s[512][4];
    __shared__ float part[4][128][4];
    __shared__ float Y[4][128];

    const int tid = threadIdx.x;
    const int col = tid & 127;
    const int ks  = tid >> 7;
    const int b0  = blockIdx.x * 4;

    *(float4*)&h_s[tid][0] = *(const float4*)&hT[(size_t)tid * B + b0];
    __syncthreads();

    float a0 = 0.f, a1 = 0.f, a2 = 0.f, a3 = 0.f;
    const float* wp = WdecT + (size_t)ks * 128 * 128 + col;
    #pragma unroll 8
    for (int k = 0; k < 128; ++k) {
        const float w = wp[(size_t)k * 128];
        const float4 hq = *(const float4*)&h_s[ks * 128 + k][0];
        a0 = fmaf(w, hq.x, a0); a1 = fmaf(w, hq.y, a1);
        a2 = fmaf(w, hq.z, a2); a3 = fmaf(w, hq.w, a3);
    }
    part[ks][col][0] = a0; part[ks][col][1] = a1;
    part[ks][col][2] = a2; part[ks][col][3] = a3;
    __syncthreads();
    if (ks == 0) {
        const float bd = (col < 123) ? bdec[col] : 0.0f;
        #pragma unroll
        for (int j = 0; j < 4; ++j)
            Y[j][col] = part[0][col][j] + part[1][col][j] + part[2][col][j]
                      + part[3][col][j] + bd;
    }
    __syncthreads();

    if (tid < 256)
        gmm_sample(Y[tid >> 6], geps, penu, out, t, b0 + (tid >> 6), tid & 63);
}

// ---------------- latent chain ----------------
__global__ __launch_bounds__(256) void latent2(
    const float* __restrict__ hfT, const float* __restrict__ hbT,
    const float* __restrict__ Wmu, const float* __restrict__ bmu,
    const float* __restrict__ Wsig, const float* __restrict__ bsig,
    const float* __restrict__ zepsT, float* __restrict__ zT)
{
    const int lane = threadIdx.x & 63;
    const int wv   = __builtin_amdgcn_readfirstlane(threadIdx.x >> 6);
    const int b    = blockIdx.x * 64 + lane;
    const int n0   = blockIdx.y * 8 + wv * 2;

    float am[2] = {}, as2[2] = {};
    #pragma unroll 4
    for (int k0 = 0; k0 < 2 * EH; k0 += 4) {
        const float* hsrc = (k0 < EH) ? hfT : hbT;
        const int kk = k0 & (EH - 1);
        const float a0 = hsrc[(size_t)(kk + 0) * B + b];
        const float a1 = hsrc[(size_t)(kk + 1) * B + b];
        const float a2 = hsrc[(size_t)(kk + 2) * B + b];
        const float a3 = hsrc[(size_t)(kk + 3) * B + b];
        #pragma unroll
        for (int j = 0; j < 2; ++j) {
            const float4 wm = *(const float4*)&Wmu[((size_t)(n0 + j)) * (2 * EH) + k0];
            const float4 ws = *(const float4*)&Wsig[((size_t)(n0 + j)) * (2 * EH) + k0];
            float u = am[j], v = as2[j];
            u = fmaf(a0, wm.x, u); u = fmaf(a1, wm.y, u); u = fmaf(a2, wm.z, u); u = fmaf(a3, wm.w, u);
            v = fmaf(a0, ws.x, v); v = fmaf(a1, ws.y, v); v = fmaf(a2, ws.z, v); v = fmaf(a3, ws.w, v);
            am[j] = u; as2[j] = v;
        }
    }
    #pragma unroll
    for (int j = 0; j < 2; ++j) {
        const int n = n0 + j;
        const float mu = am[j] + bmu[n];
        const float sg = expf(0.5f * (as2[j] + bsig[n]));
        zT[(size_t)n * B + b] = fmaf(sg, zepsT[(size_t)n * B + b], mu);
    }
}

__global__ __launch_bounds__(256) void h02(
    const float* __restrict__ zT, const float* __restrict__ Wh0,
    const float* __restrict__ bh0, float* __restrict__ hT)
{
    const int lane = threadIdx.x & 63;
    const int wv   = __builtin_amdgcn_readfirstlane(threadIdx.x >> 6);
    const int b    = blockIdx.x * 64 + lane;
    const int n0   = blockIdx.y * 32 + wv * 8;

    float acc[8] = {};
    #pragma unroll 2
    for (int k0 = 0; k0 < ZS; k0 += 4) {
        const float a0 = zT[(size_t)(k0 + 0) * B + b];
        const float a1 = zT[(size_t)(k0 + 1) * B + b];
        const float a2 = zT[(size_t)(k0 + 2) * B + b];
        const float a3 = zT[(size_t)(k0 + 3) * B + b];
        #pragma unroll
        for (int r = 0; r < 8; ++r) {
            const float4 w = *(const float4*)&Wh0[((size_t)(n0 + r)) * ZS + k0];
            float v = acc[r];
            v = fmaf(a0, w.x, v); v = fmaf(a1, w.y, v);
            v = fmaf(a2, w.z, v); v = fmaf(a3, w.w, v);
            acc[r] = v;
        }
    }
    #pragma unroll
    for (int r = 0; r < 8; ++r)
        hT[(size_t)(n0 + r) * B + b] = tanhf(acc[r] + bh0[n0 + r]);
}

__global__ __launch_bounds__(256) void cz2(
    const float* __restrict__ zT, const float* __restrict__ Wih,
    const float* __restrict__ bias, float* __restrict__ CzT)
{
    const int lane = threadIdx.x & 63;
    const int wv   = __builtin_amdgcn_readfirstlane(threadIdx.x >> 6);
    const int b    = blockIdx.x * 64 + lane;
    const int r0   = blockIdx.y * 32 + wv * 8;

    float acc[8] = {};
    #pragma unroll 4
    for (int k = 0; k < ZS; ++k) {
        const float a = zT[(size_t)k * B + b];
        #pragma unroll
        for (int r = 0; r < 8; ++r)
            acc[r] = fmaf(a, Wih[(size_t)(r0 + r) * 133 + 5 + k], acc[r]);
    }
    #pragma unroll
    for (int r = 0; r < 8; ++r)
        CzT[(size_t)(r0 + r) * B + b] = acc[r] + bias[r0 + r];
}

extern "C" void kernel_launch(void* const* d_in, const int* in_sizes, int n_in,
                              void* d_out, int out_size, void* d_ws, size_t ws_size,
                              hipStream_t stream)
{
    (void)in_sizes; (void)n_in; (void)out_size; (void)ws_size;

    const float* s      = (const float*)d_in[0];
    const float* WihF   = (const float*)d_in[1];
    const float* WhhF   = (const float*)d_in[2];
    const float* bF     = (const float*)d_in[3];
    const float* WihB   = (const float*)d_in[4];
    const float* WhhB   = (const float*)d_in[5];
    const float* bB     = (const float*)d_in[6];
    const float* Wmu    = (const float*)d_in[7];
    const float* bmu    = (const float*)d_in[8];
    const float* Wsig   = (const float*)d_in[9];
    const float* bsig   = (const float*)d_in[10];
    const float* Wh0    = (const float*)d_in[11];
    const float* bh0    = (const float*)d_in[12];
    const float* decWih = (const float*)d_in[13];
    const float* decWhh = (const float*)d_in[14];
    const float* decB   = (const float*)d_in[15];
    const float* Wdec   = (const float*)d_in[16];
    const float* bdec   = (const float*)d_in[17];
    const float* zeps   = (const float*)d_in[18];
    const float* geps   = (const float*)d_in[19];
    const float* penu   = (const float*)d_in[20];

    float* out = (float*)d_out;
    float* p   = (float*)d_ws;

    float* hf0  = p; p += 131072;   // zeroed
    float* hb0  = p; p += 131072;   // zeroed
    float* cf   = p; p += 131072;   // zeroed
    float* cb   = p; p += 131072;   // zeroed
    float* cdT  = p; p += 262144;   // zeroed
    float* hf1  = p; p += 131072;
    float* hb1  = p; p += 131072;
    float* hA   = p; p += 262144;
    float* hB   = p; p += 262144;
    float* zT   = p; p += 65536;
    float* CzT  = p; p += 1048576;
    float* zepsT= p; p += 65536;
    float* WdecT= p; p += 65536;
    float* sT   = p; p += 327680;   // [128][5][512]

    hipMemsetAsync((void*)hf0, 0, (size_t)(4 * 131072 + 262144) * sizeof(float), stream);

    transpose_pad<<<dim3(256, 1, 1), 256, 0, stream>>>(zeps, zepsT, B, ZS, B, 0, 0);
    transpose_pad<<<dim3(256, 1, 1), 256, 0, stream>>>(Wdec, WdecT, 123, DH, 128, 0, 0);
    transpose_pad<<<dim3(10, 1, SEQL), 256, 0, stream>>>(s, sT, B, PT, B, (long)B * PT, (long)B * PT);

    for (int t = 0; t < SEQL; ++t) {
        const float* hfin = (t & 1) ? hf1 : hf0;  float* hfout = (t & 1) ? hf0 : hf1;
        const float* hbin = (t & 1) ? hb1 : hb0;  float* hbout = (t & 1) ? hb0 : hb1;
        enc_step6<<<dim3(512), 512, 0, stream>>>(
            sT, WihF, WhhF, bF, WihB, WhhB, bB,
            hfin, hfout, cf, hbin, hbout, cb, t);
    }
    // t=127 (odd) wrote hf0/hb0
    latent2<<<dim3(8, 16), 256, 0, stream>>>(hf0, hb0, Wmu, bmu, Wsig, bsig, zepsT, zT);
    h02<<<dim3(8, 16), 256, 0, stream>>>(zT, Wh0, bh0, hA);
    cz2<<<dim3(8, 64), 256, 0, stream>>>(zT, decWih, decB, CzT);

    for (int t = 0; t < NMAXT; ++t) {
        const float* hin = (t & 1) ? hB : hA;
        float* hout      = (t & 1) ? hA : hB;
        dec_step6<<<dim3(512), 512, 0, stream>>>(
            hin, hout, cdT, CzT, decWhh, decWih,
            t ? (out + (size_t)(t - 1) * B * 5) : out, t);
        ysamp6<<<dim3(128), 512, 0, stream>>>(hout, WdecT, bdec, geps, penu, out, t);
    }
}

// Round 10
// 10021.058 us; speedup vs baseline: 1.0840x; 1.0005x over previous
//
#include <hip/hip_runtime.h>
#include <math.h>

#define B     512
#define SEQL  128
#define PT    5
#define EH    256
#define ZS    128
#define DH    512
#define NM    20
#define NMAXT 256

typedef float f2 __attribute__((ext_vector_type(2)));

__device__ __forceinline__ float sigf(float x) { return 1.0f / (1.0f + expf(-x)); }

// packed: acc[m][0..3] (f2 pairs over 8 batches) += ww * {p0..p3}
#define PK4(m, ww, p0, p1, p2, p3)                                \
    acc[m][0] = ww * p0 + acc[m][0]; acc[m][1] = ww * p1 + acc[m][1]; \
    acc[m][2] = ww * p2 + acc[m][2]; acc[m][3] = ww * p3 + acc[m][3];

#define XSUM(v) v += __shfl_xor(v,1); v += __shfl_xor(v,2); v += __shfl_xor(v,4); \
                v += __shfl_xor(v,8); v += __shfl_xor(v,16); v += __shfl_xor(v,32);

// GMM sampler body: y[128] in LDS, writes out[(step*B + b)*5]
__device__ __forceinline__ void gmm_sample(
    const float* __restrict__ y, const float* __restrict__ geps,
    const float* __restrict__ penu, float* __restrict__ out,
    int step, int b, int lane)
{
    const int m = lane;
    float pv = (m < NM) ? y[6 * m] : -1e30f;
    float mm = pv;
    mm = fmaxf(mm, __shfl_xor(mm, 1));  mm = fmaxf(mm, __shfl_xor(mm, 2));
    mm = fmaxf(mm, __shfl_xor(mm, 4));  mm = fmaxf(mm, __shfl_xor(mm, 8));
    mm = fmaxf(mm, __shfl_xor(mm, 16)); mm = fmaxf(mm, __shfl_xor(mm, 32));
    float pe = 0.f, tx = 0.f, ty = 0.f;
    if (m < NM) {
        pe = expf(pv - mm);
        const float mx = y[6 * m + 1], my = y[6 * m + 2];
        const float sx = expf(y[6 * m + 3]), sy = expf(y[6 * m + 4]);
        const float cor = tanhf(y[6 * m + 5]);
        const float l21 = cor / sx;
        const float l22 = sqrtf(fmaxf(sy * sy - l21 * l21, 1e-6f));
        const float* ep = &geps[(((size_t)step * B) + b) * (NM * 2) + 2 * m];
        const float e1 = ep[0], e2 = ep[1];
        tx = pe * fmaf(sx, e1, mx);
        ty = pe * (my + fmaf(l21, e1, l22 * e2));
    }
    XSUM(pe) XSUM(tx) XSUM(ty)
    if (lane == 0) {
        const float q0 = y[120], q1 = y[121], q2 = y[122];
        const float qm = fmaxf(q0, fmaxf(q1, q2));
        const float e0 = expf(q0 - qm), e1q = expf(q1 - qm), e2q = expf(q2 - qm);
        const float qs = e0 + e1q + e2q;
        const float* u = &penu[(((size_t)step * B) + b) * 3];
        float* o = &out[(((size_t)step * B) + b) * 5];
        o[0] = tx / pe;
        o[1] = ty / pe;
        o[2] = (u[0] < e0  / qs) ? 1.f : 0.f;
        o[3] = (u[1] < e1q / qs) ? 1.f : 0.f;
        o[4] = (u[2] < e2q / qs) ? 1.f : 0.f;
    }
}

// ---------- generic transpose with zero-pad: out[c*rpad + r] (per z-slice) ----------
__global__ void transpose_pad(const float* __restrict__ in, float* __restrict__ out,
                              int rows, int cols, int rpad, long islice, long oslice)
{
    const float* ip = in + (size_t)blockIdx.z * islice;
    float* op = out + (size_t)blockIdx.z * oslice;
    int idx = blockIdx.x * 256 + threadIdx.x;
    if (idx >= cols * rpad) return;
    int c = idx / rpad, r = idx - c * rpad;
    op[idx] = (r < rows) ? ip[(size_t)r * cols + c] : 0.0f;
}

// =======================================================================
// Encoder step. grid 512: x = dir*256 + bg*32 + ng. block 512 = 8 waves.
// Tile: 32 gate-rows (4g x 8n) x 64 b. Waves 8-way k-split (32 k each).
// G-phase uses packed f2 math (v_pk_fma_f32).
// =======================================================================
__global__ __launch_bounds__(512, 4) void enc_step6(
    const float* __restrict__ sT,   // [SEQL][PT][B]
    const float* __restrict__ WihF, const float* __restrict__ WhhF, const float* __restrict__ bF,
    const float* __restrict__ WihB, const float* __restrict__ WhhB, const float* __restrict__ bB,
    const float* __restrict__ hfin, float* __restrict__ hfout, float* __restrict__ cf,
    const float* __restrict__ hbin, float* __restrict__ hbout, float* __restrict__ cb,
    int t)
{
    __shared__ float lds[17408];

    const int tid = threadIdx.x;
    const int x   = blockIdx.x;
    const int ng  = x & 31;
    const int bg  = (x >> 5) & 7;
    const int dir = x >> 8;
    const int n0  = ng * 8;
    const int b0  = bg * 64;

    const float* Whh  = dir ? WhhB : WhhF;
    const float* Wih  = dir ? WihB : WihF;
    const float* bias = dir ? bB   : bF;
    const float* hin  = dir ? hbin : hfin;
    float* hout       = dir ? hbout: hfout;
    float* c          = dir ? cb   : cf;
    const int ts = dir ? (SEQL - 1 - t) : t;

    // ---- pointwise-phase prefetch (resolves under G compute) ----
    const int pn = tid & 7;
    const int pc = tid >> 3;
    const int pb = b0 + pc;
    const size_t pidx = (size_t)(n0 + pn) * B + pb;
    const float cold = c[pidx];
    const float x0 = sT[((size_t)ts * PT + 0) * B + pb];
    const float x1 = sT[((size_t)ts * PT + 1) * B + pb];
    const float x2 = sT[((size_t)ts * PT + 2) * B + pb];
    const float x3 = sT[((size_t)ts * PT + 3) * B + pb];
    const float x4 = sT[((size_t)ts * PT + 4) * B + pb];

    // ---- stage W (32 KB): XOR-swizzled ----
    #pragma unroll
    for (int i = 0; i < 4; ++i) {
        const int fidx = i * 512 + tid;
        const int w   = fidx >> 9;
        const int rem = fidx & 511;
        const int r   = rem >> 4, s5 = rem & 15;
        const int g   = r >> 3, nn = r & 7;
        const float4 wv4 = *(const float4*)&Whh[(size_t)(g * EH + n0 + nn) * EH + w * 64 + s5 * 4];
        *(float4*)&lds[((w * 32 + r) * 16 + (s5 ^ ((r >> 2) & 7))) * 4] = wv4;
    }
    __syncthreads();

    const int lane = tid & 63;
    const int wv   = tid >> 6;
    const int ri   = lane & 7;
    const int bi   = lane >> 3;
    const int wq   = wv >> 1;
    const int sb   = (wv & 1) * 8;
    const float* hcol = hin + b0 + bi * 8;

    f2 acc[4][4];
    #pragma unroll
    for (int m = 0; m < 4; ++m)
        #pragma unroll
        for (int j = 0; j < 4; ++j) acc[m][j] = (f2){0.f, 0.f};

    #pragma unroll 2
    for (int j4 = 0; j4 < 8; ++j4) {
        float4 a[4];
        #pragma unroll
        for (int m = 0; m < 4; ++m)
            a[m] = *(const float4*)&lds[((wq * 32 + ri * 4 + m) * 16 + (sb | (j4 ^ ri))) * 4];
        const int kb = wv * 32 + j4 * 4;
        #pragma unroll
        for (int jj = 0; jj < 4; ++jj) {
            const float* hp = hcol + (size_t)(kb + jj) * B;
            const float4 blo = *(const float4*)hp;
            const float4 bhi = *(const float4*)(hp + 4);
            const f2 p0 = {blo.x, blo.y}, p1 = {blo.z, blo.w};
            const f2 p2 = {bhi.x, bhi.y}, p3 = {bhi.z, bhi.w};
            #pragma unroll
            for (int m = 0; m < 4; ++m) {
                const float av = (jj == 0) ? a[m].x : (jj == 1) ? a[m].y : (jj == 2) ? a[m].z : a[m].w;
                const f2 ww = {av, av};
                PK4(m, ww, p0, p1, p2, p3)
            }
        }
    }
    __syncthreads();

    #pragma unroll
    for (int m = 0; m < 4; ++m) {
        float* pr = &lds[(wv * 32 + ri * 4 + m) * 68 + bi * 8];
        *(float4*)pr       = make_float4(acc[m][0].x, acc[m][0].y, acc[m][1].x, acc[m][1].y);
        *(float4*)(pr + 4) = make_float4(acc[m][2].x, acc[m][2].y, acc[m][3].x, acc[m][3].y);
    }
    __syncthreads();

    float ps[4];
    #pragma unroll
    for (int g = 0; g < 4; ++g) {
        const int r = g * 8 + pn;
        float v = 0.0f;
        #pragma unroll
        for (int w8 = 0; w8 < 8; ++w8) v += lds[(w8 * 32 + r) * 68 + pc];
        ps[g] = v;
    }

    float gv[4];
    #pragma unroll
    for (int g = 0; g < 4; ++g) {
        const int grow = g * EH + n0 + pn;
        const float* wr = Wih + (size_t)grow * PT;
        float v = ps[g] + bias[grow];
        v = fmaf(x0, wr[0], v); v = fmaf(x1, wr[1], v); v = fmaf(x2, wr[2], v);
        v = fmaf(x3, wr[3], v); v = fmaf(x4, wr[4], v);
        gv[g] = v;
    }
    const float cv = sigf(gv[1]) * cold + sigf(gv[0]) * tanhf(gv[2]);
    c[pidx] = cv;
    hout[pidx] = sigf(gv[3]) * tanhf(cv);
}

// =======================================================================
// Decoder step. grid 512: ng = x&63, bg = x>>6. block 512 = 8 waves.
// Tile: 32 gate-rows x 64 b. Waves 8-way k-split (64 k each). Packed f2 math.
// =======================================================================
__global__ __launch_bounds__(512, 4) void dec_step6(
    const float* __restrict__ hin, float* __restrict__ hout, float* __restrict__ cT,
    const float* __restrict__ CzT, const float* __restrict__ Whh,
    const float* __restrict__ Wih, const float* __restrict__ prevPt, int t)
{
    __shared__ float lds[17408];

    const int tid = threadIdx.x;
    const int x   = blockIdx.x;
    const int ng  = x & 63;
    const int bg  = x >> 6;
    const int n0  = ng * 8;
    const int b0  = bg * 64;

    // ---- pointwise-phase prefetch ----
    const int pn = tid & 7;
    const int pc = tid >> 3;
    const int pb = b0 + pc;
    const size_t pidx = (size_t)(n0 + pn) * B + pb;
    const float cold = cT[pidx];
    float p0w, p1w, p2w, p3w, p4w;
    if (t == 0) { p0w = 0.f; p1w = 0.f; p2w = 1.f; p3w = 0.f; p4w = 0.f; }
    else {
        const float* pp = &prevPt[(size_t)pb * 5];
        p0w = pp[0]; p1w = pp[1]; p2w = pp[2]; p3w = pp[3]; p4w = pp[4];
    }
    float cz[4];
    #pragma unroll
    for (int g = 0; g < 4; ++g)
        cz[g] = CzT[(size_t)(g * DH + n0 + pn) * B + pb];

    // ---- stage W (64 KB) ----
    #pragma unroll
    for (int i = 0; i < 8; ++i) {
        const int fidx = i * 512 + tid;
        const int w   = fidx >> 10;
        const int rem = fidx & 1023;
        const int r   = rem >> 5, s5 = rem & 31;
        const int g   = r >> 3, nn = r & 7;
        const int sl  = (s5 & 16) | ((s5 & 15) ^ ((r >> 2) & 7));
        const float4 wv4 = *(const float4*)&Whh[(size_t)(g * DH + n0 + nn) * DH + w * 128 + s5 * 4];
        *(float4*)&lds[((w * 32 + r) * 32 + sl) * 4] = wv4;
    }
    __syncthreads();

    const int lane = tid & 63;
    const int wv   = tid >> 6;
    const int ri   = lane & 7;
    const int bi   = lane >> 3;
    const int wq   = wv >> 1;
    const int sb   = (wv & 1) * 16;
    const float* hcol = hin + b0 + bi * 8;

    f2 acc[4][4];
    #pragma unroll
    for (int m = 0; m < 4; ++m)
        #pragma unroll
        for (int j = 0; j < 4; ++j) acc[m][j] = (f2){0.f, 0.f};

    #pragma unroll 2
    for (int j4 = 0; j4 < 16; ++j4) {
        float4 a[4];
        #pragma unroll
        for (int m = 0; m < 4; ++m)
            a[m] = *(const float4*)&lds[((wq * 32 + ri * 4 + m) * 32 + (sb | (j4 ^ ri))) * 4];
        const int kb = wv * 64 + j4 * 4;
        #pragma unroll
        for (int jj = 0; jj < 4; ++jj) {
            const float* hp = hcol + (size_t)(kb + jj) * B;
            const float4 blo = *(const float4*)hp;
            const float4 bhi = *(const float4*)(hp + 4);
            const f2 p0 = {blo.x, blo.y}, p1 = {blo.z, blo.w};
            const f2 p2 = {bhi.x, bhi.y}, p3 = {bhi.z, bhi.w};
            #pragma unroll
            for (int m = 0; m < 4; ++m) {
                const float av = (jj == 0) ? a[m].x : (jj == 1) ? a[m].y : (jj == 2) ? a[m].z : a[m].w;
                const f2 ww = {av, av};
                PK4(m, ww, p0, p1, p2, p3)
            }
        }
    }
    __syncthreads();

    #pragma unroll
    for (int m = 0; m < 4; ++m) {
        float* pr = &lds[(wv * 32 + ri * 4 + m) * 68 + bi * 8];
        *(float4*)pr       = make_float4(acc[m][0].x, acc[m][0].y, acc[m][1].x, acc[m][1].y);
        *(float4*)(pr + 4) = make_float4(acc[m][2].x, acc[m][2].y, acc[m][3].x, acc[m][3].y);
    }
    __syncthreads();

    float ps[4];
    #pragma unroll
    for (int g = 0; g < 4; ++g) {
        const int r = g * 8 + pn;
        float v = 0.0f;
        #pragma unroll
        for (int w8 = 0; w8 < 8; ++w8) v += lds[(w8 * 32 + r) * 68 + pc];
        ps[g] = v;
    }

    float gv[4];
    #pragma unroll
    for (int g = 0; g < 4; ++g) {
        const int grow = g * DH + n0 + pn;
        const float* wr = Wih + (size_t)grow * 133;
        float v = ps[g] + cz[g];
        v = fmaf(p0w, wr[0], v); v = fmaf(p1w, wr[1], v); v = fmaf(p2w, wr[2], v);
        v = fmaf(p3w, wr[3], v); v = fmaf(p4w, wr[4], v);
        gv[g] = v;
    }
    const float cv = sigf(gv[1]) * cold + sigf(gv[0]) * tanhf(gv[2]);
    cT[pidx] = cv;
    hout[pidx] = sigf(gv[3]) * tanhf(cv);
}

// =======================================================================
// Y = h @ Wdec^T + bdec fused with GMM sampler (R7-proven).
// grid 128 blocks x 512 thr; block = 4 batches x 128 cols, 4-way k-split.
// =======================================================================
__global__ __launch_bounds__(512) void ysamp6(
    const float* __restrict__ hT, const float* __restrict__ WdecT,
    const float* __restrict__ bdec,
    const float* __restrict__ geps, const float* __restrict__ penu,
    float* __restrict__ out, int t)
{
    __shared__ float h_s[512][4];
    __shared__ float part[4][128][4];
    __shared__ float Y[4][128];

    const int tid = threadIdx.x;
    const int col = tid & 127;
    const int ks  = tid >> 7;
    const int b0  = blockIdx.x * 4;

    *(float4*)&h_s[tid][0] = *(const float4*)&hT[(size_t)tid * B + b0];
    __syncthreads();

    float a0 = 0.f, a1 = 0.f, a2 = 0.f, a3 = 0.f;
    const float* wp = WdecT + (size_t)ks * 128 * 128 + col;
    #pragma unroll 8
    for (int k = 0; k < 128; ++k) {
        const float w = wp[(size_t)k * 128];
        const float4 hq = *(const float4*)&h_s[ks * 128 + k][0];
        a0 = fmaf(w, hq.x, a0); a1 = fmaf(w, hq.y, a1);
        a2 = fmaf(w, hq.z, a2); a3 = fmaf(w, hq.w, a3);
    }
    part[ks][col][0] = a0; part[ks][col][1] = a1;
    part[ks][col][2] = a2; part[ks][col][3] = a3;
    __syncthreads();
    if (ks == 0) {
        const float bd = (col < 123) ? bdec[col] : 0.0f;
        #pragma unroll
        for (int j = 0; j < 4; ++j)
            Y[j][col] = part[0][col][j] + part[1][col][j] + part[2][col][j]
                      + part[3][col][j] + bd;
    }
    __syncthreads();

    if (tid < 256)
        gmm_sample(Y[tid >> 6], geps, penu, out, t, b0 + (tid >> 6), tid & 63);
}

// ---------------- latent chain ----------------
__global__ __launch_bounds__(256) void latent2(
    const float* __restrict__ hfT, const float* __restrict__ hbT,
    const float* __restrict__ Wmu, const float* __restrict__ bmu,
    const float* __restrict__ Wsig, const float* __restrict__ bsig,
    const float* __restrict__ zepsT, float* __restrict__ zT)
{
    const int lane = threadIdx.x & 63;
    const int wv   = __builtin_amdgcn_readfirstlane(threadIdx.x >> 6);
    const int b    = blockIdx.x * 64 + lane;
    const int n0   = blockIdx.y * 8 + wv * 2;

    float am[2] = {}, as2[2] = {};
    #pragma unroll 4
    for (int k0 = 0; k0 < 2 * EH; k0 += 4) {
        const float* hsrc = (k0 < EH) ? hfT : hbT;
        const int kk = k0 & (EH - 1);
        const float a0 = hsrc[(size_t)(kk + 0) * B + b];
        const float a1 = hsrc[(size_t)(kk + 1) * B + b];
        const float a2 = hsrc[(size_t)(kk + 2) * B + b];
        const float a3 = hsrc[(size_t)(kk + 3) * B + b];
        #pragma unroll
        for (int j = 0; j < 2; ++j) {
            const float4 wm = *(const float4*)&Wmu[((size_t)(n0 + j)) * (2 * EH) + k0];
            const float4 ws = *(const float4*)&Wsig[((size_t)(n0 + j)) * (2 * EH) + k0];
            float u = am[j], v = as2[j];
            u = fmaf(a0, wm.x, u); u = fmaf(a1, wm.y, u); u = fmaf(a2, wm.z, u); u = fmaf(a3, wm.w, u);
            v = fmaf(a0, ws.x, v); v = fmaf(a1, ws.y, v); v = fmaf(a2, ws.z, v); v = fmaf(a3, ws.w, v);
            am[j] = u; as2[j] = v;
        }
    }
    #pragma unroll
    for (int j = 0; j < 2; ++j) {
        const int n = n0 + j;
        const float mu = am[j] + bmu[n];
        const float sg = expf(0.5f * (as2[j] + bsig[n]));
        zT[(size_t)n * B + b] = fmaf(sg, zepsT[(size_t)n * B + b], mu);
    }
}

__global__ __launch_bounds__(256) void h02(
    const float* __restrict__ zT, const float* __restrict__ Wh0,
    const float* __restrict__ bh0, float* __restrict__ hT)
{
    const int lane = threadIdx.x & 63;
    const int wv   = __builtin_amdgcn_readfirstlane(threadIdx.x >> 6);
    const int b    = blockIdx.x * 64 + lane;
    const int n0   = blockIdx.y * 32 + wv * 8;

    float acc[8] = {};
    #pragma unroll 2
    for (int k0 = 0; k0 < ZS; k0 += 4) {
        const float a0 = zT[(size_t)(k0 + 0) * B + b];
        const float a1 = zT[(size_t)(k0 + 1) * B + b];
        const float a2 = zT[(size_t)(k0 + 2) * B + b];
        const float a3 = zT[(size_t)(k0 + 3) * B + b];
        #pragma unroll
        for (int r = 0; r < 8; ++r) {
            const float4 w = *(const float4*)&Wh0[((size_t)(n0 + r)) * ZS + k0];
            float v = acc[r];
            v = fmaf(a0, w.x, v); v = fmaf(a1, w.y, v);
            v = fmaf(a2, w.z, v); v = fmaf(a3, w.w, v);
            acc[r] = v;
        }
    }
    #pragma unroll
    for (int r = 0; r < 8; ++r)
        hT[(size_t)(n0 + r) * B + b] = tanhf(acc[r] + bh0[n0 + r]);
}

__global__ __launch_bounds__(256) void cz2(
    const float* __restrict__ zT, const float* __restrict__ Wih,
    const float* __restrict__ bias, float* __restrict__ CzT)
{
    const int lane = threadIdx.x & 63;
    const int wv   = __builtin_amdgcn_readfirstlane(threadIdx.x >> 6);
    const int b    = blockIdx.x * 64 + lane;
    const int r0   = blockIdx.y * 32 + wv * 8;

    float acc[8] = {};
    #pragma unroll 4
    for (int k = 0; k < ZS; ++k) {
        const float a = zT[(size_t)k * B + b];
        #pragma unroll
        for (int r = 0; r < 8; ++r)
            acc[r] = fmaf(a, Wih[(size_t)(r0 + r) * 133 + 5 + k], acc[r]);
    }
    #pragma unroll
    for (int r = 0; r < 8; ++r)
        CzT[(size_t)(r0 + r) * B + b] = acc[r] + bias[r0 + r];
}

extern "C" void kernel_launch(void* const* d_in, const int* in_sizes, int n_in,
                              void* d_out, int out_size, void* d_ws, size_t ws_size,
                              hipStream_t stream)
{
    (void)in_sizes; (void)n_in; (void)out_size; (void)ws_size;

    const float* s      = (const float*)d_in[0];
    const float* WihF   = (const float*)d_in[1];
    const float* WhhF   = (const float*)d_in[2];
    const float* bF     = (const float*)d_in[3];
    const float* WihB   = (const float*)d_in[4];
    const float* WhhB   = (const float*)d_in[5];
    const float* bB     = (const float*)d_in[6];
    const float* Wmu    = (const float*)d_in[7];
    const float* bmu    = (const float*)d_in[8];
    const float* Wsig   = (const float*)d_in[9];
    const float* bsig   = (const float*)d_in[10];
    const float* Wh0    = (const float*)d_in[11];
    const float* bh0    = (const float*)d_in[12];
    const float* decWih = (const float*)d_in[13];
    const float* decWhh = (const float*)d_in[14];
    const float* decB   = (const float*)d_in[15];
    const float* Wdec   = (const float*)d_in[16];
    const float* bdec   = (const float*)d_in[17];
    const float* zeps   = (const float*)d_in[18];
    const float* geps   = (const float*)d_in[19];
    const float* penu   = (const float*)d_in[20];

    float* out = (float*)d_out;
    float* p   = (float*)d_ws;

    float* hf0  = p; p += 131072;   // zeroed
    float* hb0  = p; p += 131072;   // zeroed
    float* cf   = p; p += 131072;   // zeroed
    float* cb   = p; p += 131072;   // zeroed
    float* cdT  = p; p += 262144;   // zeroed
    float* hf1  = p; p += 131072;
    float* hb1  = p; p += 131072;
    float* hA   = p; p += 262144;
    float* hB   = p; p += 262144;
    float* zT   = p; p += 65536;
    float* CzT  = p; p += 1048576;
    float* zepsT= p; p += 65536;
    float* WdecT= p; p += 65536;
    float* sT   = p; p += 327680;   // [128][5][512]

    hipMemsetAsync((void*)hf0, 0, (size_t)(4 * 131072 + 262144) * sizeof(float), stream);

    transpose_pad<<<dim3(256, 1, 1), 256, 0, stream>>>(zeps, zepsT, B, ZS, B, 0, 0);
    transpose_pad<<<dim3(256, 1, 1), 256, 0, stream>>>(Wdec, WdecT, 123, DH, 128, 0, 0);
    transpose_pad<<<dim3(10, 1, SEQL), 256, 0, stream>>>(s, sT, B, PT, B, (long)B * PT, (long)B * PT);

    for (int t = 0; t < SEQL; ++t) {
        const float* hfin = (t & 1) ? hf1 : hf0;  float* hfout = (t & 1) ? hf0 : hf1;
        const float* hbin = (t & 1) ? hb1 : hb0;  float* hbout = (t & 1) ? hb0 : hb1;
        enc_step6<<<dim3(512), 512, 0, stream>>>(
            sT, WihF, WhhF, bF, WihB, WhhB, bB,
            hfin, hfout, cf, hbin, hbout, cb, t);
    }
    // t=127 (odd) wrote hf0/hb0
    latent2<<<dim3(8, 16), 256, 0, stream>>>(hf0, hb0, Wmu, bmu, Wsig, bsig, zepsT, zT);
    h02<<<dim3(8, 16), 256, 0, stream>>>(zT, Wh0, bh0, hA);
    cz2<<<dim3(8, 64), 256, 0, stream>>>(zT, decWih, decB, CzT);

    for (int t = 0; t < NMAXT; ++t) {
        const float* hin = (t & 1) ? hB : hA;
        float* hout      = (t & 1) ? hA : hB;
        dec_step6<<<dim3(512), 512, 0, stream>>>(
            hin, hout, cdT, CzT, decWhh, decWih,
            t ? (out + (size_t)(t - 1) * B * 5) : out, t);
        ysamp6<<<dim3(128), 512, 0, stream>>>(hout, WdecT, bdec, geps, penu, out, t);
    }
}